// Round 5
// baseline (358.177 us; speedup 1.0000x reference)
//
#include <hip/hip_runtime.h>
#include <hip/hip_fp16.h>

// Problem constants (fixed by the reference file)
#define M_DIM 16384   // B*S = 4*4096
#define N_DIM 4096    // DOUT
#define K_DIM 4096    // DIN

typedef __attribute__((ext_vector_type(16))) float f32x16;
typedef __attribute__((ext_vector_type(4)))  int   i32x4;
typedef __attribute__((ext_vector_type(8)))  int   i32x8;

// ---------------------------------------------------------------------------
// Quantize fp32 (fp16-exact values) -> fp8 RNE, emitting the 32x32x64 MFMA
// fragment-order tiled layout for 256-row blocks:
//   out = [nrow/256][K/64] tiles of 16384 B.
//   tile byte p = sb*2048 + half*1024 + l*16 + b   (sb 0..7, half 0..1,
//   l 0..63, b 0..15) holds element
//     row = tile_r*256 + sb*32 + (l&31)
//     k   = tile_k*64  + (l>>5)*32 + half*16 + b
//   so GEMM lane l reads its v_mfma_f32_32x32x64_f8f6f4 fragment as two
//   contiguous ds_read_b128 (base, base+1024) -> 0 bank conflicts; staging
//   is linear (global_load_lds-compatible).
// E4M3=true -> OCP e4m3fn (weight); false -> OCP e5m2 (activations).
// ---------------------------------------------------------------------------
template<bool E4M3>
__global__ __launch_bounds__(256) void quant_tile_kernel(
    const float* __restrict__ in,   // [R, K_DIM] row-major f32
    uint4* __restrict__ out,        // tiled fp8 bytes, R*K_DIM/16 groups
    int ngrp)
{
  int t = blockIdx.x * 256 + threadIdx.x;
  if (t >= ngrp) return;
  const int g    = t & 1023;        // 16-byte group within 16 KiB tile
  const int tile = t >> 10;
  const int kt   = tile & 63;       // K/64 = 64 K-tiles
  const int bt   = tile >> 6;       // 256-row block
  const int sb   = g >> 7;          // 32-row sub-block (0..7)
  const int half = (g >> 6) & 1;
  const int l    = g & 63;
  const int row  = bt * 256 + sb * 32 + (l & 31);
  const int k    = kt * 64 + (l >> 5) * 32 + half * 16;

  const float4* p = reinterpret_cast<const float4*>(in + (size_t)row * K_DIM + k);
  float4 v0 = p[0], v1 = p[1], v2 = p[2], v3 = p[3];
  int w0 = 0, w1 = 0, w2 = 0, w3 = 0;
  if (E4M3) {
    w0 = __builtin_amdgcn_cvt_pk_fp8_f32(v0.x, v0.y, w0, false);
    w0 = __builtin_amdgcn_cvt_pk_fp8_f32(v0.z, v0.w, w0, true);
    w1 = __builtin_amdgcn_cvt_pk_fp8_f32(v1.x, v1.y, w1, false);
    w1 = __builtin_amdgcn_cvt_pk_fp8_f32(v1.z, v1.w, w1, true);
    w2 = __builtin_amdgcn_cvt_pk_fp8_f32(v2.x, v2.y, w2, false);
    w2 = __builtin_amdgcn_cvt_pk_fp8_f32(v2.z, v2.w, w2, true);
    w3 = __builtin_amdgcn_cvt_pk_fp8_f32(v3.x, v3.y, w3, false);
    w3 = __builtin_amdgcn_cvt_pk_fp8_f32(v3.z, v3.w, w3, true);
  } else {
    w0 = __builtin_amdgcn_cvt_pk_bf8_f32(v0.x, v0.y, w0, false);
    w0 = __builtin_amdgcn_cvt_pk_bf8_f32(v0.z, v0.w, w0, true);
    w1 = __builtin_amdgcn_cvt_pk_bf8_f32(v1.x, v1.y, w1, false);
    w1 = __builtin_amdgcn_cvt_pk_bf8_f32(v1.z, v1.w, w1, true);
    w2 = __builtin_amdgcn_cvt_pk_bf8_f32(v2.x, v2.y, w2, false);
    w2 = __builtin_amdgcn_cvt_pk_bf8_f32(v2.z, v2.w, w2, true);
    w3 = __builtin_amdgcn_cvt_pk_bf8_f32(v3.x, v3.y, w3, false);
    w3 = __builtin_amdgcn_cvt_pk_bf8_f32(v3.z, v3.w, w3, true);
  }
  out[t] = make_uint4((unsigned)w0, (unsigned)w1, (unsigned)w2, (unsigned)w3);
}

// ---------------------------------------------------------------------------
// Deep-pipelined MX-fp8 GEMM, register-level SW pipeline (frags one K-tile
// ahead, unroll x2 for static reg sets): 256x256 tile, BK=64, 8 waves (2Mx4N),
// per-wave 128x64 = acc[4][2] f32x16.
// Per K-tile: STAGE(kt+2) ; vmcnt(4)+barrier ; ds_read frags(kt+1) overlapped
// with 8 MFMA on frags(kt) ; lgkmcnt(0)+barrier. 2 barriers/K-tile, counted
// vmcnt never 0 in the loop.
// ---------------------------------------------------------------------------
__global__ __launch_bounds__(512, 2) void gemm_fp8_kernel(
    const unsigned char* __restrict__ Aq,   // tiled [64][64][16384] e5m2
    const unsigned char* __restrict__ Wq,   // tiled [16][64][16384] e4m3
    const float* __restrict__ bias,         // [N] fp16-exact values in f32
    float* __restrict__ C)                  // [M,N] f32 (fp16-rounded values)
{
  __shared__ __align__(16) unsigned char lds[65536];   // buf0 | buf1, each {A 16K, B 16K}

  const int tid  = threadIdx.x;
  const int lane = tid & 63;
  const int wave = tid >> 6;
  const int wr   = wave >> 2;               // 0..1 -> 128 rows
  const int wc   = wave & 3;                // 0..3 -> 64 cols

  // T1: XCD-aware bijective swizzle (nwg = 1024, 1024 % 8 == 0)
  const int bid = blockIdx.x;
  const int swz = (bid & 7) * 128 + (bid >> 3);
  const int bmi = swz >> 4;                 // 0..63
  const int bni = swz & 15;                 // 0..15

  const unsigned char* tA = Aq + (size_t)bmi * 64 * 16384;
  const unsigned char* tB = Wq + (size_t)bni * 64 * 16384;

  const size_t t16 = (size_t)tid * 16;      // per-lane global offset
  const int    w1k = wave * 1024;           // wave-uniform LDS offset

#define STAGE(gbase, ldsoff)                                                \
  __builtin_amdgcn_global_load_lds(                                         \
      (const __attribute__((address_space(1))) void*)((gbase) + t16),       \
      (__attribute__((address_space(3))) void*)(lds + (ldsoff) + w1k), 16, 0, 0)

  // Read one 32x32x64 fragment (two contiguous b128 at base, base+1024).
#define RDFRAG(dst, byteoff)                                                \
  { const unsigned char* _p = lds + (byteoff) + lane * 16;                  \
    i32x4 _lo = *(const i32x4*)_p;                                          \
    i32x4 _hi = *(const i32x4*)(_p + 1024);                                 \
    dst = i32x8{_lo.x, _lo.y, _lo.z, _lo.w, _hi.x, _hi.y, _hi.z, _hi.w}; }

#define MFMA(d, a, b)                                                       \
  d = __builtin_amdgcn_mfma_scale_f32_32x32x64_f8f6f4(                      \
      a, b, d, 1 /*A=e5m2*/, 0 /*B=e4m3*/, 0, 0x7F7F7F7F, 0, 0x7F7F7F7F)

  const int aoff = wr * 8192;               // A frag base within a buf
  const int boff = 16384 + wc * 4096;       // B frag base within a buf

  f32x16 acc[4][2] = {};
  i32x8 aE0, aE1, aE2, aE3, bE0, bE1;       // frags, even tiles
  i32x8 aO0, aO1, aO2, aO3, bO0, bO1;       // frags, odd tiles

  // ---- Prologue: stage tile 0 -> buf0, tile 1 -> buf1
  STAGE(tA,              0);
  STAGE(tA + 8192,       8192);
  STAGE(tB,              16384);
  STAGE(tB + 8192,       24576);
  __builtin_amdgcn_sched_barrier(0);
  STAGE(tA + 16384,          32768);
  STAGE(tA + 16384 + 8192,   40960);
  STAGE(tB + 16384,          49152);
  STAGE(tB + 16384 + 8192,   57344);
  __builtin_amdgcn_sched_barrier(0);
  asm volatile("s_waitcnt vmcnt(4)" ::: "memory");   // tile 0 landed
  __builtin_amdgcn_s_barrier();
  RDFRAG(aE0, aoff + 0 * 2048);  RDFRAG(aE1, aoff + 1 * 2048);
  RDFRAG(aE2, aoff + 2 * 2048);  RDFRAG(aE3, aoff + 3 * 2048);
  RDFRAG(bE0, boff + 0 * 2048);  RDFRAG(bE1, boff + 1 * 2048);
  asm volatile("s_waitcnt lgkmcnt(0)" ::: "memory");
  __builtin_amdgcn_sched_barrier(0);
  __builtin_amdgcn_s_barrier();                      // buf0 free for restage

  for (int kt = 0; kt < 64; kt += 2) {
    // ===== EVEN: compute tile kt (E frags); stage kt+2 -> buf0;
    //             read frags of tile kt+1 (O) from buf1, overlapped with MFMA.
    {
      const size_t tp = (size_t)((kt + 2) & 63) * 16384;
      STAGE(tA + tp,        0);
      STAGE(tA + tp + 8192, 8192);
      STAGE(tB + tp,        16384);
      STAGE(tB + tp + 8192, 24576);
      asm volatile("s_waitcnt vmcnt(4)" ::: "memory");   // tile kt+1 landed
      __builtin_amdgcn_s_barrier();                      // ...on all waves
      RDFRAG(aO0, 32768 + aoff + 0 * 2048);
      RDFRAG(aO1, 32768 + aoff + 1 * 2048);
      RDFRAG(aO2, 32768 + aoff + 2 * 2048);
      RDFRAG(aO3, 32768 + aoff + 3 * 2048);
      RDFRAG(bO0, 32768 + boff + 0 * 2048);
      RDFRAG(bO1, 32768 + boff + 1 * 2048);
      __builtin_amdgcn_s_setprio(1);
      MFMA(acc[0][0], aE0, bE0); MFMA(acc[0][1], aE0, bE1);
      MFMA(acc[1][0], aE1, bE0); MFMA(acc[1][1], aE1, bE1);
      MFMA(acc[2][0], aE2, bE0); MFMA(acc[2][1], aE2, bE1);
      MFMA(acc[3][0], aE3, bE0); MFMA(acc[3][1], aE3, bE1);
      __builtin_amdgcn_s_setprio(0);
      __builtin_amdgcn_sched_barrier(0);
      asm volatile("s_waitcnt lgkmcnt(0)" ::: "memory"); // O frags in regs
      __builtin_amdgcn_sched_barrier(0);
      __builtin_amdgcn_s_barrier();                      // buf1 free for restage
    }
    // ===== ODD: compute tile kt+1 (O frags); stage kt+3 -> buf1;
    //            read frags of tile kt+2 (E) from buf0, overlapped with MFMA.
    {
      const size_t tp = (size_t)((kt + 3) & 63) * 16384;
      STAGE(tA + tp,        32768);
      STAGE(tA + tp + 8192, 40960);
      STAGE(tB + tp,        49152);
      STAGE(tB + tp + 8192, 57344);
      asm volatile("s_waitcnt vmcnt(4)" ::: "memory");   // tile kt+2 landed
      __builtin_amdgcn_s_barrier();
      RDFRAG(aE0, aoff + 0 * 2048);
      RDFRAG(aE1, aoff + 1 * 2048);
      RDFRAG(aE2, aoff + 2 * 2048);
      RDFRAG(aE3, aoff + 3 * 2048);
      RDFRAG(bE0, boff + 0 * 2048);
      RDFRAG(bE1, boff + 1 * 2048);
      __builtin_amdgcn_s_setprio(1);
      MFMA(acc[0][0], aO0, bO0); MFMA(acc[0][1], aO0, bO1);
      MFMA(acc[1][0], aO1, bO0); MFMA(acc[1][1], aO1, bO1);
      MFMA(acc[2][0], aO2, bO0); MFMA(acc[2][1], aO2, bO1);
      MFMA(acc[3][0], aO3, bO0); MFMA(acc[3][1], aO3, bO1);
      __builtin_amdgcn_s_setprio(0);
      __builtin_amdgcn_sched_barrier(0);
      asm volatile("s_waitcnt lgkmcnt(0)" ::: "memory");
      __builtin_amdgcn_sched_barrier(0);
      __builtin_amdgcn_s_barrier();                      // buf0 free for restage
    }
  }
#undef STAGE
#undef RDFRAG
#undef MFMA

  // Epilogue: +bias, round through fp16 (matches reference), store f32.
  // 32x32 C/D layout: col = lane&31, row = (r&3) + 8*(r>>2) + 4*(lane>>5).
  #pragma unroll
  for (int n = 0; n < 2; ++n) {
    const int col = bni * 256 + wc * 64 + n * 32 + (lane & 31);
    const float bv = bias[col];
    #pragma unroll
    for (int m = 0; m < 4; ++m) {
      const int rbase = bmi * 256 + wr * 128 + m * 32 + ((lane >> 5) << 2);
      #pragma unroll
      for (int r = 0; r < 16; ++r) {
        const int row = rbase + (r & 3) + 8 * (r >> 2);
        C[(size_t)row * N_DIM + col] =
            __half2float(__float2half_rn(acc[m][n][r] + bv));
      }
    }
  }
}

// ---------------------------------------------------------------------------
extern "C" void kernel_launch(void* const* d_in, const int* in_sizes, int n_in,
                              void* d_out, int out_size, void* d_ws, size_t ws_size,
                              hipStream_t stream) {
  const float* x  = (const float*)d_in[0];   // [B,S,DIN] fp16-exact values in f32
  const float* w  = (const float*)d_in[1];   // [DOUT,DIN]
  const float* bs = (const float*)d_in[2];   // [DOUT]
  float* out = (float*)d_out;

  // Workspace: xq = 64 MiB e5m2 (tiled), wq = 16 MiB e4m3 (tiled)
  unsigned char* xq = (unsigned char*)d_ws;
  unsigned char* wq = (unsigned char*)d_ws + (size_t)M_DIM * K_DIM;

  const int ngx = (M_DIM * K_DIM) / 16;   // 4,194,304 groups
  const int ngw = (N_DIM * K_DIM) / 16;   // 1,048,576 groups
  quant_tile_kernel<false><<<ngx / 256, 256, 0, stream>>>(x, (uint4*)xq, ngx);
  quant_tile_kernel<true ><<<ngw / 256, 256, 0, stream>>>(w, (uint4*)wq, ngw);

  gemm_fp8_kernel<<<1024, 512, 0, stream>>>(xq, wq, bs, out);
}